// Round 6
// baseline (499.627 us; speedup 1.0000x reference)
//
#include <hip/hip_runtime.h>
#include <stdint.h>

// ---------------------------------------------------------------------------
// 2-layer GCN. g = (xW) row-scaled by dinv, stored BF16 (MFMA bf16 GEMM).
// out[d] = dinv[d] * (sum_{s in N(d)} g[s] + g[d]) + b, f32 accumulate.
// R6: column-sliced aggregation — cg = blockIdx & 7 pins each 32-col slice of
// g (3.2 MB) to one XCD's L2 (blocks round-robin across XCDs), turning the
// random gather from L3/HBM-served (230 MB FETCH) into L2-served.
// ---------------------------------------------------------------------------

typedef unsigned short u16;
typedef __bf16 bf16x8 __attribute__((ext_vector_type(8)));
typedef float f32x4 __attribute__((ext_vector_type(4)));
typedef unsigned short us8 __attribute__((ext_vector_type(8)));
typedef unsigned short us4 __attribute__((ext_vector_type(4)));

#define BSHIFT 8                  // bucket = dst >> 8 (256 nodes/bucket)
#define BSTRIDE 6144              // record slots per bucket (mean 5102, +14 sigma)
#define EPT 8                     // edges per thread in scatter
#define TILE (256 * EPT)

__device__ __forceinline__ float bf2f(u16 u) {
    union { unsigned i; float f; } c;
    c.i = ((unsigned)u) << 16;
    return c.f;
}
__device__ __forceinline__ u16 f2bf(float f) {
    union { float f; unsigned i; } c;
    c.f = f;
    unsigned i = c.i;
    return (u16)((i + 0x7FFF + ((i >> 16) & 1)) >> 16);   // RNE
}

// ---------------------------------------------------------------------------
// CSR build, pass 1: tile-sorted scatter of (dst,src) records into bucket
// segments (write-local; one cursor atomic per tile-bucket).
// ---------------------------------------------------------------------------
__global__ __launch_bounds__(256) void scatter_kernel(const int* __restrict__ src,
        const int* __restrict__ dst, int* __restrict__ bcursor,
        int2* __restrict__ rec, int E) {
    __shared__ int cnt[256], lcur[256], gbase[256];
    const int t = threadIdx.x;
    const int base = blockIdx.x * TILE;
    cnt[t] = 0;
    __syncthreads();
    int d[EPT], s[EPT], b[EPT];
#pragma unroll
    for (int k = 0; k < EPT; k++) {
        int e = base + t + k * 256;
        if (e < E) {
            d[k] = dst[e];
            s[k] = src[e];
            b[k] = d[k] >> BSHIFT;
            atomicAdd(&cnt[b[k]], 1);
        } else b[k] = -1;
    }
    __syncthreads();
    int c = cnt[t];
    if (c > 0) gbase[t] = atomicAdd(&bcursor[t], c);
    lcur[t] = 0;
    __syncthreads();
#pragma unroll
    for (int k = 0; k < EPT; k++) {
        if (b[k] >= 0) {
            int r = atomicAdd(&lcur[b[k]], 1);
            rec[(size_t)b[k] * BSTRIDE + gbase[b[k]] + r] = make_int2(d[k], s[k]);
        }
    }
}

// pass 2: exclusive scan of bucket counts (one block) -> bbase; row_ptr[n]=E
__global__ __launch_bounds__(256) void bucket_scan(const int* __restrict__ bcursor,
        int* __restrict__ bbase, int* __restrict__ row_ptr, int NB, int n, int E) {
    __shared__ int sc[256];
    int t = threadIdx.x;
    int v = (t < NB) ? bcursor[t] : 0;
    sc[t] = v;
    __syncthreads();
    for (int off = 1; off < 256; off <<= 1) {
        int u = (t >= off) ? sc[t - off] : 0;
        __syncthreads();
        sc[t] += u;
        __syncthreads();
    }
    if (t < NB) bbase[t] = sc[t] - v;      // exclusive
    if (t == 0) { bbase[NB] = E; row_ptr[n] = E; }
}

// pass 3: per-bucket local count + scan + scatter into csr_src; emits
// row_ptr and dinv.
__global__ __launch_bounds__(256) void bucket_build(const int2* __restrict__ rec,
        const int* __restrict__ bcursor, const int* __restrict__ bbase,
        int* __restrict__ row_ptr, float* __restrict__ dinv,
        int* __restrict__ csr_src, int n) {
    __shared__ int cnt[256], loff[256], sc[256];
    const int b = blockIdx.x;
    const int t = threadIdx.x;
    const int m = bcursor[b];
    const int base = bbase[b];
    const int2* r = rec + (size_t)b * BSTRIDE;
    cnt[t] = 0;
    __syncthreads();
    for (int i = t; i < m; i += 256)
        atomicAdd(&cnt[r[i].x & 255], 1);
    __syncthreads();
    int c = cnt[t];
    sc[t] = c;
    __syncthreads();
    for (int off = 1; off < 256; off <<= 1) {
        int u = (t >= off) ? sc[t - off] : 0;
        __syncthreads();
        sc[t] += u;
        __syncthreads();
    }
    loff[t] = sc[t] - c;
    int node = (b << BSHIFT) + t;
    if (node < n) {
        row_ptr[node] = base + loff[t];
        dinv[node] = 1.0f / sqrtf((float)c + 1.0f);
    }
    __syncthreads();
    sc[t] = loff[t];
    __syncthreads();
    for (int i = t; i < m; i += 256) {
        int2 e = r[i];
        int idx = atomicAdd(&sc[e.x & 255], 1);
        csr_src[base + idx] = e.y;
    }
}

// W[256][256] f32 (k-major) -> Wt[256][256] bf16 (n-major: Wt[n][k])
__global__ void wt_kernel(const float* __restrict__ W, u16* __restrict__ Wt) {
    int t = blockIdx.x * blockDim.x + threadIdx.x;   // 65536
    int k = t >> 8, nn = t & 255;
    Wt[((size_t)nn << 8) + k] = f2bf(W[t]);
}

// ---------------------------------------------------------------------------
// MFMA GEMM: g[M x 256] = bf16( dinv[row] * (A[M x 256] @ W) )
// 128x128 tile, 4 waves 2x2, K=256. B slice staged full-K once; A per K-tile.
// ---------------------------------------------------------------------------
template<bool AF32>
__global__ __launch_bounds__(256, 2) void mfma_gemm(const void* __restrict__ Ap,
        const u16* __restrict__ Wt, const float* __restrict__ dinv,
        u16* __restrict__ g, int M) {
    __shared__ u16 Bs[128][264];    // [col][k] 67584 B
    __shared__ u16 As[128][40];     // [row][k-tile] 10240 B
    const int tid = threadIdx.x;
    const int row0 = blockIdx.x * 128;
    const int col0 = blockIdx.y * 128;

    {   // stage B slice: Wt rows [col0, col0+128), all 256 k
        const int col = tid >> 1;
        const int bhalf = tid & 1;
        const u16* srcp = Wt + (((size_t)(col0 + col)) << 8) + bhalf * 128;
#pragma unroll
        for (int q = 0; q < 16; q++)
            *(us8*)&Bs[col][bhalf * 128 + q * 8] = *(const us8*)(srcp + q * 8);
    }

    const int lane = tid & 63;
    const int w = tid >> 6;
    const int wr = w >> 1, wc = w & 1;
    const int l15 = lane & 15, kg = lane >> 4;

    f32x4 acc[4][4];
#pragma unroll
    for (int mi = 0; mi < 4; mi++)
#pragma unroll
        for (int ni = 0; ni < 4; ni++)
            acc[mi][ni] = (f32x4){0.f, 0.f, 0.f, 0.f};

    const int srow = tid >> 1;
    const int shalf = tid & 1;
    const int grow = row0 + srow;

    for (int k0 = 0; k0 < 256; k0 += 32) {
        if (AF32) {
            const float* srcp = (const float*)Ap + ((size_t)grow << 8) + k0 + shalf * 16;
            float4 v[4];
#pragma unroll
            for (int q = 0; q < 4; q++)
                v[q] = (grow < M) ? *(const float4*)(srcp + q * 4)
                                  : make_float4(0.f, 0.f, 0.f, 0.f);
            u16 tmp[16];
#pragma unroll
            for (int q = 0; q < 4; q++) {
                tmp[q * 4 + 0] = f2bf(v[q].x); tmp[q * 4 + 1] = f2bf(v[q].y);
                tmp[q * 4 + 2] = f2bf(v[q].z); tmp[q * 4 + 3] = f2bf(v[q].w);
            }
            *(us8*)&As[srow][shalf * 16]     = *(us8*)&tmp[0];
            *(us8*)&As[srow][shalf * 16 + 8] = *(us8*)&tmp[8];
        } else {
            const u16* srcp = (const u16*)Ap + ((size_t)grow << 8) + k0 + shalf * 16;
            us8 z = {0, 0, 0, 0, 0, 0, 0, 0};
            us8 a0 = (grow < M) ? *(const us8*)srcp       : z;
            us8 a1 = (grow < M) ? *(const us8*)(srcp + 8) : z;
            *(us8*)&As[srow][shalf * 16]     = a0;
            *(us8*)&As[srow][shalf * 16 + 8] = a1;
        }
        __syncthreads();
        bf16x8 af[4], bfv[4];
#pragma unroll
        for (int mi = 0; mi < 4; mi++)
            af[mi] = *(const bf16x8*)&As[wr * 64 + mi * 16 + l15][kg * 8];
#pragma unroll
        for (int ni = 0; ni < 4; ni++)
            bfv[ni] = *(const bf16x8*)&Bs[wc * 64 + ni * 16 + l15][k0 + kg * 8];
#pragma unroll
        for (int mi = 0; mi < 4; mi++)
#pragma unroll
            for (int ni = 0; ni < 4; ni++)
                acc[mi][ni] = __builtin_amdgcn_mfma_f32_16x16x32_bf16(
                    af[mi], bfv[ni], acc[mi][ni], 0, 0, 0);
        __syncthreads();
    }

#pragma unroll
    for (int mi = 0; mi < 4; mi++) {
#pragma unroll
        for (int r = 0; r < 4; r++) {
            int gr = row0 + wr * 64 + mi * 16 + kg * 4 + r;
            if (gr < M) {
                float s = dinv[gr];
                u16* dstp = g + ((size_t)gr << 8) + col0 + wc * 64 + l15;
#pragma unroll
                for (int ni = 0; ni < 4; ni++)
                    dstp[ni * 16] = f2bf(acc[mi][ni][r] * s);
            }
        }
    }
}

// ---------------------------------------------------------------------------
// Column-sliced aggregation. blockIdx.x = cg + 8*nb; cg selects a 32-column
// slice (64 B of each g row) and, via round-robin block->XCD dispatch, pins
// that slice to one XCD's L2. One wave per (node, cg): lane = (edge-slot
// es=lane>>4, col-pair cl=lane&15); ushort2 gathers (16 lanes = 1 line/edge);
// x2 unroll; shfl_xor reduce across slots. Full-line stores.
// ---------------------------------------------------------------------------
template<bool OUT16>
__global__ __launch_bounds__(256) void agg_kernel(const u16* __restrict__ g,
        const int* __restrict__ csr_src, const int* __restrict__ row_ptr,
        const float* __restrict__ dinv, const float* __restrict__ bias,
        void* __restrict__ outp, int n, int do_relu) {
    const int cg = blockIdx.x & 7;
    const int nb = blockIdx.x >> 3;
    const int wid = threadIdx.x >> 6;
    const int lane = threadIdx.x & 63;
    const int node = nb * 4 + wid;
    if (node >= n) return;
    const int es = lane >> 4;          // edge slot 0..3
    const int cl = lane & 15;          // col pair 0..15
    const int coff = cg * 32 + cl * 2; // element offset within row

    const int jb = row_ptr[node], je = row_ptr[node + 1];
    float ax = 0.f, ay = 0.f, bx2 = 0.f, by2 = 0.f;
    int j = jb + es;
    for (; j + 4 < je; j += 8) {
        int s0 = csr_src[j];
        int s1 = csr_src[j + 4];
        ushort2 v0 = *(const ushort2*)(g + ((size_t)s0 << 8) + coff);
        ushort2 v1 = *(const ushort2*)(g + ((size_t)s1 << 8) + coff);
        ax += bf2f(v0.x); ay += bf2f(v0.y);
        bx2 += bf2f(v1.x); by2 += bf2f(v1.y);
    }
    if (j < je) {
        int s0 = csr_src[j];
        ushort2 v0 = *(const ushort2*)(g + ((size_t)s0 << 8) + coff);
        ax += bf2f(v0.x); ay += bf2f(v0.y);
    }
    ax += bx2; ay += by2;
    if (es == 0) {                     // self-loop term, added once
        ushort2 v = *(const ushort2*)(g + ((size_t)node << 8) + coff);
        ax += bf2f(v.x); ay += bf2f(v.y);
    }
    // reduce across the 4 edge slots (lanes l, l^16, l^32, l^48)
    ax += __shfl_xor(ax, 16, 64); ay += __shfl_xor(ay, 16, 64);
    ax += __shfl_xor(ax, 32, 64); ay += __shfl_xor(ay, 32, 64);

    if (es == 0) {
        float dn = dinv[node];
        float ox = ax * dn + bias[coff];
        float oy = ay * dn + bias[coff + 1];
        if (do_relu) { ox = fmaxf(ox, 0.f); oy = fmaxf(oy, 0.f); }
        if (OUT16) {
            ushort2 ov = { f2bf(ox), f2bf(oy) };
            *(ushort2*)((u16*)outp + ((size_t)node << 8) + coff) = ov;
        } else {
            float2 ov = { ox, oy };
            *(float2*)((float*)outp + ((size_t)node << 8) + coff) = ov;
        }
    }
}

extern "C" void kernel_launch(void* const* d_in, const int* in_sizes, int n_in,
                              void* d_out, int out_size, void* d_ws, size_t ws_size,
                              hipStream_t stream) {
    // inputs: 0 gene_ind_vec (unused), 1 edge_index, 2 embedding, 3 W1, 4 b1, 5 W2, 6 b2
    const int*   edge_index = (const int*)d_in[1];
    const float* embedding  = (const float*)d_in[2];
    const float* W1 = (const float*)d_in[3];
    const float* b1 = (const float*)d_in[4];
    const float* W2 = (const float*)d_in[5];
    const float* b2 = (const float*)d_in[6];

    const int E = in_sizes[1] / 2;
    const int n = in_sizes[2] / 256;
    const int* src = edge_index;
    const int* dst = edge_index + E;
    const int NB = (n + 255) >> BSHIFT;     // buckets

    char* ws = (char*)d_ws;
    int* row_ptr = (int*)ws;    ws += ((size_t)n + 1) * 4;
    float* dinv = (float*)ws;   ws += (size_t)n * 4;
    int* bcursor = (int*)ws;    ws += 256 * 4;
    int* bbase = (int*)ws;      ws += 257 * 4;
    int* csr_src = (int*)ws;    ws += (size_t)E * 4;
    u16* Wt1 = (u16*)ws;        ws += 65536 * 2;
    u16* Wt2 = (u16*)ws;        ws += 65536 * 2;
    ws = (char*)(((uintptr_t)ws + 127) & ~(uintptr_t)127);
    int2* rec = (int2*)ws;      ws += (size_t)NB * BSTRIDE * 8;
    ws = (char*)(((uintptr_t)ws + 127) & ~(uintptr_t)127);
    u16* g = (u16*)ws;          // n*256 bf16 (25.6 MB)
    u16* x1 = (u16*)d_out;      // bf16 x1 scratch in d_out; consumed by gemm2
                                // before final agg overwrites d_out

    hipMemsetAsync(bcursor, 0, 256 * 4, stream);
    scatter_kernel<<<(E + TILE - 1) / TILE, 256, 0, stream>>>(src, dst, bcursor, rec, E);
    bucket_scan<<<1, 256, 0, stream>>>(bcursor, bbase, row_ptr, NB, n, E);
    bucket_build<<<NB, 256, 0, stream>>>(rec, bcursor, bbase, row_ptr, dinv, csr_src, n);
    wt_kernel<<<256, 256, 0, stream>>>(W1, Wt1);
    wt_kernel<<<256, 256, 0, stream>>>(W2, Wt2);

    dim3 gg((n + 127) / 128, 2);
    const int agg_grid = ((n + 3) / 4) * 8;
    // layer 1: g1 = bf16(dinv*(X@W1)); x1 = bf16(relu(dinv*(agg+self)+b1))
    mfma_gemm<true><<<gg, 256, 0, stream>>>(embedding, Wt1, dinv, g, n);
    agg_kernel<true><<<agg_grid, 256, 0, stream>>>(g, csr_src, row_ptr, dinv, b1, x1, n, 1);
    // layer 2: g2 = bf16(dinv*(x1@W2)); out = dinv*(agg+self)+b2 (f32)
    mfma_gemm<false><<<gg, 256, 0, stream>>>(x1, Wt2, dinv, g, n);
    agg_kernel<false><<<agg_grid, 256, 0, stream>>>(g, csr_src, row_ptr, dinv, b2, (float*)d_out, n, 0);
}

// Round 7
// 255.525 us; speedup vs baseline: 1.9553x; 1.9553x over previous
//
#include <hip/hip_runtime.h>
#include <stdint.h>

// ---------------------------------------------------------------------------
// 2-layer GCN. g = (xW) row-scaled by dinv, stored BF16 (MFMA bf16 GEMM).
// out[d] = dinv[d] * (sum_{s in N(d)} g[s] + g[d]) + b, f32 accumulate.
// R7: revert agg to R5 full-row form (74us, at the ~3.9 TB/s random-gather
// service ceiling; R6's column-slicing regressed 2.6x). Merge small prep
// kernels to cut launch gaps.
// ---------------------------------------------------------------------------

typedef unsigned short u16;
typedef __bf16 bf16x8 __attribute__((ext_vector_type(8)));
typedef float f32x4 __attribute__((ext_vector_type(4)));
typedef unsigned short us8 __attribute__((ext_vector_type(8)));
typedef unsigned short us4 __attribute__((ext_vector_type(4)));

#define BSHIFT 8                  // bucket = dst >> 8 (256 nodes/bucket)
#define BSTRIDE 6144              // record slots per bucket (mean 5102, +14 sigma)
#define EPT 8                     // edges per thread in scatter
#define TILE (256 * EPT)

__device__ __forceinline__ float bf2f(u16 u) {
    union { unsigned i; float f; } c;
    c.i = ((unsigned)u) << 16;
    return c.f;
}
__device__ __forceinline__ u16 f2bf(float f) {
    union { float f; unsigned i; } c;
    c.f = f;
    unsigned i = c.i;
    return (u16)((i + 0x7FFF + ((i >> 16) & 1)) >> 16);   // RNE
}

// ---------------------------------------------------------------------------
// prep: zero bucket cursors + transpose/convert both weight matrices.
// W[256][256] f32 (k-major) -> Wt[256][256] bf16 (n-major: Wt[n][k]).
// One launch (256 blocks x 256 thr) replacing memset + 2x wt_kernel.
// ---------------------------------------------------------------------------
__global__ __launch_bounds__(256) void prep_kernel(const float* __restrict__ W1,
        const float* __restrict__ W2, u16* __restrict__ Wt1, u16* __restrict__ Wt2,
        int* __restrict__ bcursor) {
    int t = blockIdx.x * 256 + threadIdx.x;          // 0..65535
    int k = t >> 8, nn = t & 255;
    size_t idx = ((size_t)nn << 8) + k;
    Wt1[idx] = f2bf(W1[t]);
    Wt2[idx] = f2bf(W2[t]);
    if (blockIdx.x == 0) bcursor[threadIdx.x] = 0;
}

// ---------------------------------------------------------------------------
// CSR build, pass 1: tile-sorted scatter of (dst,src) records into bucket
// segments (write-local; one cursor atomic per tile-bucket).
// ---------------------------------------------------------------------------
__global__ __launch_bounds__(256) void scatter_kernel(const int* __restrict__ src,
        const int* __restrict__ dst, int* __restrict__ bcursor,
        int2* __restrict__ rec, int E) {
    __shared__ int cnt[256], lcur[256], gbase[256];
    const int t = threadIdx.x;
    const int base = blockIdx.x * TILE;
    cnt[t] = 0;
    __syncthreads();
    int d[EPT], s[EPT], b[EPT];
#pragma unroll
    for (int k = 0; k < EPT; k++) {
        int e = base + t + k * 256;
        if (e < E) {
            d[k] = dst[e];
            s[k] = src[e];
            b[k] = d[k] >> BSHIFT;
            atomicAdd(&cnt[b[k]], 1);
        } else b[k] = -1;
    }
    __syncthreads();
    int c = cnt[t];
    if (c > 0) gbase[t] = atomicAdd(&bcursor[t], c);
    lcur[t] = 0;
    __syncthreads();
#pragma unroll
    for (int k = 0; k < EPT; k++) {
        if (b[k] >= 0) {
            int r = atomicAdd(&lcur[b[k]], 1);
            rec[(size_t)b[k] * BSTRIDE + gbase[b[k]] + r] = make_int2(d[k], s[k]);
        }
    }
}

// pass 2: exclusive scan of bucket counts (one block) -> bbase; row_ptr[n]=E
__global__ __launch_bounds__(256) void bucket_scan(const int* __restrict__ bcursor,
        int* __restrict__ bbase, int* __restrict__ row_ptr, int NB, int n, int E) {
    __shared__ int sc[256];
    int t = threadIdx.x;
    int v = (t < NB) ? bcursor[t] : 0;
    sc[t] = v;
    __syncthreads();
    for (int off = 1; off < 256; off <<= 1) {
        int u = (t >= off) ? sc[t - off] : 0;
        __syncthreads();
        sc[t] += u;
        __syncthreads();
    }
    if (t < NB) bbase[t] = sc[t] - v;      // exclusive
    if (t == 0) { bbase[NB] = E; row_ptr[n] = E; }
}

// pass 3: per-bucket local count + scan + scatter into csr_src; emits
// row_ptr and dinv.
__global__ __launch_bounds__(256) void bucket_build(const int2* __restrict__ rec,
        const int* __restrict__ bcursor, const int* __restrict__ bbase,
        int* __restrict__ row_ptr, float* __restrict__ dinv,
        int* __restrict__ csr_src, int n) {
    __shared__ int cnt[256], loff[256], sc[256];
    const int b = blockIdx.x;
    const int t = threadIdx.x;
    const int m = bcursor[b];
    const int base = bbase[b];
    const int2* r = rec + (size_t)b * BSTRIDE;
    cnt[t] = 0;
    __syncthreads();
    for (int i = t; i < m; i += 256)
        atomicAdd(&cnt[r[i].x & 255], 1);
    __syncthreads();
    int c = cnt[t];
    sc[t] = c;
    __syncthreads();
    for (int off = 1; off < 256; off <<= 1) {
        int u = (t >= off) ? sc[t - off] : 0;
        __syncthreads();
        sc[t] += u;
        __syncthreads();
    }
    loff[t] = sc[t] - c;
    int node = (b << BSHIFT) + t;
    if (node < n) {
        row_ptr[node] = base + loff[t];
        dinv[node] = 1.0f / sqrtf((float)c + 1.0f);
    }
    __syncthreads();
    sc[t] = loff[t];
    __syncthreads();
    for (int i = t; i < m; i += 256) {
        int2 e = r[i];
        int idx = atomicAdd(&sc[e.x & 255], 1);
        csr_src[base + idx] = e.y;
    }
}

// ---------------------------------------------------------------------------
// MFMA GEMM: g[M x 256] = bf16( dinv[row] * (A[M x 256] @ W) )
// A f32 (layer1, converted in staging) or bf16 (layer2). W given as Wt[n][k].
// 128x128 tile, 4 waves 2x2, K=256. B slice staged full-K once (67.6 KB LDS);
// A staged per 32-K tile (10 KB).
// ---------------------------------------------------------------------------
template<bool AF32>
__global__ __launch_bounds__(256, 2) void mfma_gemm(const void* __restrict__ Ap,
        const u16* __restrict__ Wt, const float* __restrict__ dinv,
        u16* __restrict__ g, int M) {
    __shared__ u16 Bs[128][264];    // [col][k] 67584 B
    __shared__ u16 As[128][40];     // [row][k-tile] 10240 B
    const int tid = threadIdx.x;
    const int row0 = blockIdx.x * 128;
    const int col0 = blockIdx.y * 128;

    {   // stage B slice: Wt rows [col0, col0+128), all 256 k
        const int col = tid >> 1;
        const int bhalf = tid & 1;
        const u16* srcp = Wt + (((size_t)(col0 + col)) << 8) + bhalf * 128;
#pragma unroll
        for (int q = 0; q < 16; q++)
            *(us8*)&Bs[col][bhalf * 128 + q * 8] = *(const us8*)(srcp + q * 8);
    }

    const int lane = tid & 63;
    const int w = tid >> 6;
    const int wr = w >> 1, wc = w & 1;
    const int l15 = lane & 15, kg = lane >> 4;

    f32x4 acc[4][4];
#pragma unroll
    for (int mi = 0; mi < 4; mi++)
#pragma unroll
        for (int ni = 0; ni < 4; ni++)
            acc[mi][ni] = (f32x4){0.f, 0.f, 0.f, 0.f};

    const int srow = tid >> 1;
    const int shalf = tid & 1;
    const int grow = row0 + srow;

    for (int k0 = 0; k0 < 256; k0 += 32) {
        if (AF32) {
            const float* srcp = (const float*)Ap + ((size_t)grow << 8) + k0 + shalf * 16;
            float4 v[4];
#pragma unroll
            for (int q = 0; q < 4; q++)
                v[q] = (grow < M) ? *(const float4*)(srcp + q * 4)
                                  : make_float4(0.f, 0.f, 0.f, 0.f);
            u16 tmp[16];
#pragma unroll
            for (int q = 0; q < 4; q++) {
                tmp[q * 4 + 0] = f2bf(v[q].x); tmp[q * 4 + 1] = f2bf(v[q].y);
                tmp[q * 4 + 2] = f2bf(v[q].z); tmp[q * 4 + 3] = f2bf(v[q].w);
            }
            *(us8*)&As[srow][shalf * 16]     = *(us8*)&tmp[0];
            *(us8*)&As[srow][shalf * 16 + 8] = *(us8*)&tmp[8];
        } else {
            const u16* srcp = (const u16*)Ap + ((size_t)grow << 8) + k0 + shalf * 16;
            us8 z = {0, 0, 0, 0, 0, 0, 0, 0};
            us8 a0 = (grow < M) ? *(const us8*)srcp       : z;
            us8 a1 = (grow < M) ? *(const us8*)(srcp + 8) : z;
            *(us8*)&As[srow][shalf * 16]     = a0;
            *(us8*)&As[srow][shalf * 16 + 8] = a1;
        }
        __syncthreads();
        bf16x8 af[4], bfv[4];
#pragma unroll
        for (int mi = 0; mi < 4; mi++)
            af[mi] = *(const bf16x8*)&As[wr * 64 + mi * 16 + l15][kg * 8];
#pragma unroll
        for (int ni = 0; ni < 4; ni++)
            bfv[ni] = *(const bf16x8*)&Bs[wc * 64 + ni * 16 + l15][k0 + kg * 8];
#pragma unroll
        for (int mi = 0; mi < 4; mi++)
#pragma unroll
            for (int ni = 0; ni < 4; ni++)
                acc[mi][ni] = __builtin_amdgcn_mfma_f32_16x16x32_bf16(
                    af[mi], bfv[ni], acc[mi][ni], 0, 0, 0);
        __syncthreads();
    }

#pragma unroll
    for (int mi = 0; mi < 4; mi++) {
#pragma unroll
        for (int r = 0; r < 4; r++) {
            int gr = row0 + wr * 64 + mi * 16 + kg * 4 + r;
            if (gr < M) {
                float s = dinv[gr];
                u16* dstp = g + ((size_t)gr << 8) + col0 + wc * 64 + l15;
#pragma unroll
                for (int ni = 0; ni < 4; ni++)
                    dstp[ni * 16] = f2bf(acc[mi][ni][r] * s);
            }
        }
    }
}

// ---------------------------------------------------------------------------
// Aggregation (R5 form): one wave per node, lane = 4 cols (ushort4 bf16
// gather, 8B/lane = 512B/edge/wave). f32 accumulate, x8 unroll. Epilogue
// scales by dinv, adds bias, optional relu; f32 or bf16 output.
// ---------------------------------------------------------------------------
template<bool OUT16>
__global__ __launch_bounds__(256) void agg_kernel(const u16* __restrict__ g,
        const int* __restrict__ csr_src, const int* __restrict__ row_ptr,
        const float* __restrict__ dinv, const float* __restrict__ bias,
        void* __restrict__ outp, int n, int do_relu) {
    int wid = threadIdx.x >> 6;
    int lane = threadIdx.x & 63;
    int node = blockIdx.x * 4 + wid;
    if (node >= n) return;
    int jb = row_ptr[node], je = row_ptr[node + 1];
    const size_t co = (size_t)(lane * 4);
    float4 a0 = make_float4(0.f, 0.f, 0.f, 0.f);
    float4 a1 = make_float4(0.f, 0.f, 0.f, 0.f);
    int j = jb;
    for (; j + 8 <= je; j += 8) {
        int s0 = csr_src[j + 0], s1 = csr_src[j + 1];
        int s2 = csr_src[j + 2], s3 = csr_src[j + 3];
        int s4 = csr_src[j + 4], s5 = csr_src[j + 5];
        int s6 = csr_src[j + 6], s7 = csr_src[j + 7];
        ushort4 v0 = *(const ushort4*)(g + ((size_t)s0 << 8) + co);
        ushort4 v1 = *(const ushort4*)(g + ((size_t)s1 << 8) + co);
        ushort4 v2 = *(const ushort4*)(g + ((size_t)s2 << 8) + co);
        ushort4 v3 = *(const ushort4*)(g + ((size_t)s3 << 8) + co);
        ushort4 v4 = *(const ushort4*)(g + ((size_t)s4 << 8) + co);
        ushort4 v5 = *(const ushort4*)(g + ((size_t)s5 << 8) + co);
        ushort4 v6 = *(const ushort4*)(g + ((size_t)s6 << 8) + co);
        ushort4 v7 = *(const ushort4*)(g + ((size_t)s7 << 8) + co);
        a0.x += bf2f(v0.x); a0.y += bf2f(v0.y); a0.z += bf2f(v0.z); a0.w += bf2f(v0.w);
        a1.x += bf2f(v1.x); a1.y += bf2f(v1.y); a1.z += bf2f(v1.z); a1.w += bf2f(v1.w);
        a0.x += bf2f(v2.x); a0.y += bf2f(v2.y); a0.z += bf2f(v2.z); a0.w += bf2f(v2.w);
        a1.x += bf2f(v3.x); a1.y += bf2f(v3.y); a1.z += bf2f(v3.z); a1.w += bf2f(v3.w);
        a0.x += bf2f(v4.x); a0.y += bf2f(v4.y); a0.z += bf2f(v4.z); a0.w += bf2f(v4.w);
        a1.x += bf2f(v5.x); a1.y += bf2f(v5.y); a1.z += bf2f(v5.z); a1.w += bf2f(v5.w);
        a0.x += bf2f(v6.x); a0.y += bf2f(v6.y); a0.z += bf2f(v6.z); a0.w += bf2f(v6.w);
        a1.x += bf2f(v7.x); a1.y += bf2f(v7.y); a1.z += bf2f(v7.z); a1.w += bf2f(v7.w);
    }
    for (; j < je; ++j) {
        int s = csr_src[j];
        ushort4 v = *(const ushort4*)(g + ((size_t)s << 8) + co);
        a0.x += bf2f(v.x); a0.y += bf2f(v.y); a0.z += bf2f(v.z); a0.w += bf2f(v.w);
    }
    ushort4 gd = *(const ushort4*)(g + ((size_t)node << 8) + co);
    float dn = dinv[node];
    float4 bv = *(const float4*)(bias + co);
    float4 o;
    o.x = (a0.x + a1.x + bf2f(gd.x)) * dn + bv.x;
    o.y = (a0.y + a1.y + bf2f(gd.y)) * dn + bv.y;
    o.z = (a0.z + a1.z + bf2f(gd.z)) * dn + bv.z;
    o.w = (a0.w + a1.w + bf2f(gd.w)) * dn + bv.w;
    if (do_relu) {
        o.x = fmaxf(o.x, 0.f); o.y = fmaxf(o.y, 0.f);
        o.z = fmaxf(o.z, 0.f); o.w = fmaxf(o.w, 0.f);
    }
    if (OUT16) {
        us4 ov = { f2bf(o.x), f2bf(o.y), f2bf(o.z), f2bf(o.w) };
        *(us4*)((u16*)outp + ((size_t)node << 8) + co) = ov;
    } else {
        *(float4*)((float*)outp + ((size_t)node << 8) + co) = o;
    }
}

extern "C" void kernel_launch(void* const* d_in, const int* in_sizes, int n_in,
                              void* d_out, int out_size, void* d_ws, size_t ws_size,
                              hipStream_t stream) {
    // inputs: 0 gene_ind_vec (unused), 1 edge_index, 2 embedding, 3 W1, 4 b1, 5 W2, 6 b2
    const int*   edge_index = (const int*)d_in[1];
    const float* embedding  = (const float*)d_in[2];
    const float* W1 = (const float*)d_in[3];
    const float* b1 = (const float*)d_in[4];
    const float* W2 = (const float*)d_in[5];
    const float* b2 = (const float*)d_in[6];

    const int E = in_sizes[1] / 2;
    const int n = in_sizes[2] / 256;
    const int* src = edge_index;
    const int* dst = edge_index + E;
    const int NB = (n + 255) >> BSHIFT;     // buckets

    char* ws = (char*)d_ws;
    int* row_ptr = (int*)ws;    ws += ((size_t)n + 1) * 4;
    float* dinv = (float*)ws;   ws += (size_t)n * 4;
    int* bcursor = (int*)ws;    ws += 256 * 4;
    int* bbase = (int*)ws;      ws += 257 * 4;
    int* csr_src = (int*)ws;    ws += (size_t)E * 4;
    u16* Wt1 = (u16*)ws;        ws += 65536 * 2;
    u16* Wt2 = (u16*)ws;        ws += 65536 * 2;
    ws = (char*)(((uintptr_t)ws + 127) & ~(uintptr_t)127);
    int2* rec = (int2*)ws;      ws += (size_t)NB * BSTRIDE * 8;
    ws = (char*)(((uintptr_t)ws + 127) & ~(uintptr_t)127);
    u16* g = (u16*)ws;          // n*256 bf16 (25.6 MB)
    u16* x1 = (u16*)d_out;      // bf16 x1 scratch in d_out; consumed by gemm2
                                // before final agg overwrites d_out

    prep_kernel<<<256, 256, 0, stream>>>(W1, W2, Wt1, Wt2, bcursor);
    scatter_kernel<<<(E + TILE - 1) / TILE, 256, 0, stream>>>(src, dst, bcursor, rec, E);
    bucket_scan<<<1, 256, 0, stream>>>(bcursor, bbase, row_ptr, NB, n, E);
    bucket_build<<<NB, 256, 0, stream>>>(rec, bcursor, bbase, row_ptr, dinv, csr_src, n);

    dim3 gg((n + 127) / 128, 2);
    // layer 1: g1 = bf16(dinv*(X@W1)); x1 = bf16(relu(dinv*(agg+self)+b1))
    mfma_gemm<true><<<gg, 256, 0, stream>>>(embedding, Wt1, dinv, g, n);
    agg_kernel<true><<<(n + 3) / 4, 256, 0, stream>>>(g, csr_src, row_ptr, dinv, b1, x1, n, 1);
    // layer 2: g2 = bf16(dinv*(x1@W2)); out = dinv*(agg+self)+b2 (f32)
    mfma_gemm<false><<<gg, 256, 0, stream>>>(x1, Wt2, dinv, g, n);
    agg_kernel<false><<<(n + 3) / 4, 256, 0, stream>>>(g, csr_src, row_ptr, dinv, b2, (float*)d_out, n, 0);
}

// Round 8
// 241.942 us; speedup vs baseline: 2.0651x; 1.0561x over previous
//
#include <hip/hip_runtime.h>
#include <stdint.h>

// ---------------------------------------------------------------------------
// 2-layer GCN. g = (xW) row-scaled by dinv, stored BF16 (MFMA bf16 GEMM).
// out[d] = dinv[d] * (sum_{s in N(d)} g[s] + g[d]) + b, f32 accumulate.
// R8: per-K-tile B staging in mfma_gemm (LDS 78KB -> 20KB, 2 -> 4 blocks/CU,
// kills the 1.53-round dispatch tail). agg stays at its measured ~3.9 TB/s
// random-gather service plateau (R1/R2/R5/R7 concordant).
// ---------------------------------------------------------------------------

typedef unsigned short u16;
typedef __bf16 bf16x8 __attribute__((ext_vector_type(8)));
typedef float f32x4 __attribute__((ext_vector_type(4)));
typedef unsigned short us8 __attribute__((ext_vector_type(8)));
typedef unsigned short us4 __attribute__((ext_vector_type(4)));

#define BSHIFT 8                  // bucket = dst >> 8 (256 nodes/bucket)
#define BSTRIDE 6144              // record slots per bucket (mean 5102, +14 sigma)
#define EPT 8                     // edges per thread in scatter
#define TILE (256 * EPT)

__device__ __forceinline__ float bf2f(u16 u) {
    union { unsigned i; float f; } c;
    c.i = ((unsigned)u) << 16;
    return c.f;
}
__device__ __forceinline__ u16 f2bf(float f) {
    union { float f; unsigned i; } c;
    c.f = f;
    unsigned i = c.i;
    return (u16)((i + 0x7FFF + ((i >> 16) & 1)) >> 16);   // RNE
}

// ---------------------------------------------------------------------------
// prep: zero bucket cursors + transpose/convert both weight matrices.
// W[256][256] f32 (k-major) -> Wt[256][256] bf16 (n-major: Wt[n][k]).
// ---------------------------------------------------------------------------
__global__ __launch_bounds__(256) void prep_kernel(const float* __restrict__ W1,
        const float* __restrict__ W2, u16* __restrict__ Wt1, u16* __restrict__ Wt2,
        int* __restrict__ bcursor) {
    int t = blockIdx.x * 256 + threadIdx.x;          // 0..65535
    int k = t >> 8, nn = t & 255;
    size_t idx = ((size_t)nn << 8) + k;
    Wt1[idx] = f2bf(W1[t]);
    Wt2[idx] = f2bf(W2[t]);
    if (blockIdx.x == 0) bcursor[threadIdx.x] = 0;
}

// ---------------------------------------------------------------------------
// CSR build, pass 1: tile-sorted scatter of (dst,src) records into bucket
// segments (write-local; one cursor atomic per tile-bucket).
// ---------------------------------------------------------------------------
__global__ __launch_bounds__(256) void scatter_kernel(const int* __restrict__ src,
        const int* __restrict__ dst, int* __restrict__ bcursor,
        int2* __restrict__ rec, int E) {
    __shared__ int cnt[256], lcur[256], gbase[256];
    const int t = threadIdx.x;
    const int base = blockIdx.x * TILE;
    cnt[t] = 0;
    __syncthreads();
    int d[EPT], s[EPT], b[EPT];
#pragma unroll
    for (int k = 0; k < EPT; k++) {
        int e = base + t + k * 256;
        if (e < E) {
            d[k] = dst[e];
            s[k] = src[e];
            b[k] = d[k] >> BSHIFT;
            atomicAdd(&cnt[b[k]], 1);
        } else b[k] = -1;
    }
    __syncthreads();
    int c = cnt[t];
    if (c > 0) gbase[t] = atomicAdd(&bcursor[t], c);
    lcur[t] = 0;
    __syncthreads();
#pragma unroll
    for (int k = 0; k < EPT; k++) {
        if (b[k] >= 0) {
            int r = atomicAdd(&lcur[b[k]], 1);
            rec[(size_t)b[k] * BSTRIDE + gbase[b[k]] + r] = make_int2(d[k], s[k]);
        }
    }
}

// pass 2: exclusive scan of bucket counts (one block) -> bbase; row_ptr[n]=E
__global__ __launch_bounds__(256) void bucket_scan(const int* __restrict__ bcursor,
        int* __restrict__ bbase, int* __restrict__ row_ptr, int NB, int n, int E) {
    __shared__ int sc[256];
    int t = threadIdx.x;
    int v = (t < NB) ? bcursor[t] : 0;
    sc[t] = v;
    __syncthreads();
    for (int off = 1; off < 256; off <<= 1) {
        int u = (t >= off) ? sc[t - off] : 0;
        __syncthreads();
        sc[t] += u;
        __syncthreads();
    }
    if (t < NB) bbase[t] = sc[t] - v;      // exclusive
    if (t == 0) { bbase[NB] = E; row_ptr[n] = E; }
}

// pass 3: per-bucket local count + scan + scatter into csr_src; emits
// row_ptr and dinv.
__global__ __launch_bounds__(256) void bucket_build(const int2* __restrict__ rec,
        const int* __restrict__ bcursor, const int* __restrict__ bbase,
        int* __restrict__ row_ptr, float* __restrict__ dinv,
        int* __restrict__ csr_src, int n) {
    __shared__ int cnt[256], loff[256], sc[256];
    const int b = blockIdx.x;
    const int t = threadIdx.x;
    const int m = bcursor[b];
    const int base = bbase[b];
    const int2* r = rec + (size_t)b * BSTRIDE;
    cnt[t] = 0;
    __syncthreads();
    for (int i = t; i < m; i += 256)
        atomicAdd(&cnt[r[i].x & 255], 1);
    __syncthreads();
    int c = cnt[t];
    sc[t] = c;
    __syncthreads();
    for (int off = 1; off < 256; off <<= 1) {
        int u = (t >= off) ? sc[t - off] : 0;
        __syncthreads();
        sc[t] += u;
        __syncthreads();
    }
    loff[t] = sc[t] - c;
    int node = (b << BSHIFT) + t;
    if (node < n) {
        row_ptr[node] = base + loff[t];
        dinv[node] = 1.0f / sqrtf((float)c + 1.0f);
    }
    __syncthreads();
    sc[t] = loff[t];
    __syncthreads();
    for (int i = t; i < m; i += 256) {
        int2 e = r[i];
        int idx = atomicAdd(&sc[e.x & 255], 1);
        csr_src[base + idx] = e.y;
    }
}

// ---------------------------------------------------------------------------
// MFMA GEMM: g[M x 256] = bf16( dinv[row] * (A[M x 256] @ W) )
// A f32 (layer1, converted in staging) or bf16 (layer2). W given as Wt[n][k].
// 128x128 tile, 4 waves 2x2, K=256, per-K-tile staging of BOTH A and B
// (10 KB each, 20 KB LDS total -> 4 blocks/CU).
// mfma_f32_16x16x32_bf16 layouts: A(row=l&15, k=(l>>4)*8+j),
// B(col=l&15, k=(l>>4)*8+j), D(col=l&15, row=(l>>4)*4+r).
// ---------------------------------------------------------------------------
template<bool AF32>
__global__ __launch_bounds__(256, 4) void mfma_gemm(const void* __restrict__ Ap,
        const u16* __restrict__ Wt, const float* __restrict__ dinv,
        u16* __restrict__ g, int M) {
    __shared__ u16 As[128][40];     // [row][k] 10240 B
    __shared__ u16 Bs[128][40];     // [col][k] 10240 B
    const int tid = threadIdx.x;
    const int row0 = blockIdx.x * 128;
    const int col0 = blockIdx.y * 128;

    const int lane = tid & 63;
    const int w = tid >> 6;
    const int wr = w >> 1, wc = w & 1;
    const int l15 = lane & 15, kg = lane >> 4;

    f32x4 acc[4][4];
#pragma unroll
    for (int mi = 0; mi < 4; mi++)
#pragma unroll
        for (int ni = 0; ni < 4; ni++)
            acc[mi][ni] = (f32x4){0.f, 0.f, 0.f, 0.f};

    const int srow = tid >> 1;          // 0..127 (A row / B col)
    const int shalf = tid & 1;          // which 16-element k-half
    const int grow = row0 + srow;

    for (int k0 = 0; k0 < 256; k0 += 32) {
        // stage A rows [row0,row0+128) x k-tile
        if (AF32) {
            const float* srcp = (const float*)Ap + ((size_t)grow << 8) + k0 + shalf * 16;
            float4 v[4];
#pragma unroll
            for (int q = 0; q < 4; q++)
                v[q] = (grow < M) ? *(const float4*)(srcp + q * 4)
                                  : make_float4(0.f, 0.f, 0.f, 0.f);
            u16 tmp[16];
#pragma unroll
            for (int q = 0; q < 4; q++) {
                tmp[q * 4 + 0] = f2bf(v[q].x); tmp[q * 4 + 1] = f2bf(v[q].y);
                tmp[q * 4 + 2] = f2bf(v[q].z); tmp[q * 4 + 3] = f2bf(v[q].w);
            }
            *(us8*)&As[srow][shalf * 16]     = *(us8*)&tmp[0];
            *(us8*)&As[srow][shalf * 16 + 8] = *(us8*)&tmp[8];
        } else {
            const u16* srcp = (const u16*)Ap + ((size_t)grow << 8) + k0 + shalf * 16;
            us8 z = {0, 0, 0, 0, 0, 0, 0, 0};
            us8 a0 = (grow < M) ? *(const us8*)srcp       : z;
            us8 a1 = (grow < M) ? *(const us8*)(srcp + 8) : z;
            *(us8*)&As[srow][shalf * 16]     = a0;
            *(us8*)&As[srow][shalf * 16 + 8] = a1;
        }
        // stage B cols [col0,col0+128) x k-tile (Wt is [n][k] bf16)
        {
            const u16* srcp = Wt + (((size_t)(col0 + srow)) << 8) + k0 + shalf * 16;
            *(us8*)&Bs[srow][shalf * 16]     = *(const us8*)srcp;
            *(us8*)&Bs[srow][shalf * 16 + 8] = *(const us8*)(srcp + 8);
        }
        __syncthreads();
        bf16x8 af[4], bfv[4];
#pragma unroll
        for (int mi = 0; mi < 4; mi++)
            af[mi] = *(const bf16x8*)&As[wr * 64 + mi * 16 + l15][kg * 8];
#pragma unroll
        for (int ni = 0; ni < 4; ni++)
            bfv[ni] = *(const bf16x8*)&Bs[wc * 64 + ni * 16 + l15][kg * 8];
#pragma unroll
        for (int mi = 0; mi < 4; mi++)
#pragma unroll
            for (int ni = 0; ni < 4; ni++)
                acc[mi][ni] = __builtin_amdgcn_mfma_f32_16x16x32_bf16(
                    af[mi], bfv[ni], acc[mi][ni], 0, 0, 0);
        __syncthreads();
    }

#pragma unroll
    for (int mi = 0; mi < 4; mi++) {
#pragma unroll
        for (int r = 0; r < 4; r++) {
            int gr = row0 + wr * 64 + mi * 16 + kg * 4 + r;
            if (gr < M) {
                float s = dinv[gr];
                u16* dstp = g + ((size_t)gr << 8) + col0 + wc * 64 + l15;
#pragma unroll
                for (int ni = 0; ni < 4; ni++)
                    dstp[ni * 16] = f2bf(acc[mi][ni][r] * s);
            }
        }
    }
}

// ---------------------------------------------------------------------------
// Aggregation (R5 form): one wave per node, lane = 4 cols (ushort4 bf16
// gather, 8B/lane = 512B/edge/wave). f32 accumulate, x8 unroll. Epilogue
// scales by dinv, adds bias, optional relu; f32 or bf16 output.
// ---------------------------------------------------------------------------
template<bool OUT16>
__global__ __launch_bounds__(256) void agg_kernel(const u16* __restrict__ g,
        const int* __restrict__ csr_src, const int* __restrict__ row_ptr,
        const float* __restrict__ dinv, const float* __restrict__ bias,
        void* __restrict__ outp, int n, int do_relu) {
    int wid = threadIdx.x >> 6;
    int lane = threadIdx.x & 63;
    int node = blockIdx.x * 4 + wid;
    if (node >= n) return;
    int jb = row_ptr[node], je = row_ptr[node + 1];
    const size_t co = (size_t)(lane * 4);
    float4 a0 = make_float4(0.f, 0.f, 0.f, 0.f);
    float4 a1 = make_float4(0.f, 0.f, 0.f, 0.f);
    int j = jb;
    for (; j + 8 <= je; j += 8) {
        int s0 = csr_src[j + 0], s1 = csr_src[j + 1];
        int s2 = csr_src[j + 2], s3 = csr_src[j + 3];
        int s4 = csr_src[j + 4], s5 = csr_src[j + 5];
        int s6 = csr_src[j + 6], s7 = csr_src[j + 7];
        ushort4 v0 = *(const ushort4*)(g + ((size_t)s0 << 8) + co);
        ushort4 v1 = *(const ushort4*)(g + ((size_t)s1 << 8) + co);
        ushort4 v2 = *(const ushort4*)(g + ((size_t)s2 << 8) + co);
        ushort4 v3 = *(const ushort4*)(g + ((size_t)s3 << 8) + co);
        ushort4 v4 = *(const ushort4*)(g + ((size_t)s4 << 8) + co);
        ushort4 v5 = *(const ushort4*)(g + ((size_t)s5 << 8) + co);
        ushort4 v6 = *(const ushort4*)(g + ((size_t)s6 << 8) + co);
        ushort4 v7 = *(const ushort4*)(g + ((size_t)s7 << 8) + co);
        a0.x += bf2f(v0.x); a0.y += bf2f(v0.y); a0.z += bf2f(v0.z); a0.w += bf2f(v0.w);
        a1.x += bf2f(v1.x); a1.y += bf2f(v1.y); a1.z += bf2f(v1.z); a1.w += bf2f(v1.w);
        a0.x += bf2f(v2.x); a0.y += bf2f(v2.y); a0.z += bf2f(v2.z); a0.w += bf2f(v2.w);
        a1.x += bf2f(v3.x); a1.y += bf2f(v3.y); a1.z += bf2f(v3.z); a1.w += bf2f(v3.w);
        a0.x += bf2f(v4.x); a0.y += bf2f(v4.y); a0.z += bf2f(v4.z); a0.w += bf2f(v4.w);
        a1.x += bf2f(v5.x); a1.y += bf2f(v5.y); a1.z += bf2f(v5.z); a1.w += bf2f(v5.w);
        a0.x += bf2f(v6.x); a0.y += bf2f(v6.y); a0.z += bf2f(v6.z); a0.w += bf2f(v6.w);
        a1.x += bf2f(v7.x); a1.y += bf2f(v7.y); a1.z += bf2f(v7.z); a1.w += bf2f(v7.w);
    }
    for (; j < je; ++j) {
        int s = csr_src[j];
        ushort4 v = *(const ushort4*)(g + ((size_t)s << 8) + co);
        a0.x += bf2f(v.x); a0.y += bf2f(v.y); a0.z += bf2f(v.z); a0.w += bf2f(v.w);
    }
    ushort4 gd = *(const ushort4*)(g + ((size_t)node << 8) + co);
    float dn = dinv[node];
    float4 bv = *(const float4*)(bias + co);
    float4 o;
    o.x = (a0.x + a1.x + bf2f(gd.x)) * dn + bv.x;
    o.y = (a0.y + a1.y + bf2f(gd.y)) * dn + bv.y;
    o.z = (a0.z + a1.z + bf2f(gd.z)) * dn + bv.z;
    o.w = (a0.w + a1.w + bf2f(gd.w)) * dn + bv.w;
    if (do_relu) {
        o.x = fmaxf(o.x, 0.f); o.y = fmaxf(o.y, 0.f);
        o.z = fmaxf(o.z, 0.f); o.w = fmaxf(o.w, 0.f);
    }
    if (OUT16) {
        us4 ov = { f2bf(o.x), f2bf(o.y), f2bf(o.z), f2bf(o.w) };
        *(us4*)((u16*)outp + ((size_t)node << 8) + co) = ov;
    } else {
        *(float4*)((float*)outp + ((size_t)node << 8) + co) = o;
    }
}

extern "C" void kernel_launch(void* const* d_in, const int* in_sizes, int n_in,
                              void* d_out, int out_size, void* d_ws, size_t ws_size,
                              hipStream_t stream) {
    // inputs: 0 gene_ind_vec (unused), 1 edge_index, 2 embedding, 3 W1, 4 b1, 5 W2, 6 b2
    const int*   edge_index = (const int*)d_in[1];
    const float* embedding  = (const float*)d_in[2];
    const float* W1 = (const float*)d_in[3];
    const float* b1 = (const float*)d_in[4];
    const float* W2 = (const float*)d_in[5];
    const float* b2 = (const float*)d_in[6];

    const int E = in_sizes[1] / 2;
    const int n = in_sizes[2] / 256;
    const int* src = edge_index;
    const int* dst = edge_index + E;
    const int NB = (n + 255) >> BSHIFT;     // buckets

    char* ws = (char*)d_ws;
    int* row_ptr = (int*)ws;    ws += ((size_t)n + 1) * 4;
    float* dinv = (float*)ws;   ws += (size_t)n * 4;
    int* bcursor = (int*)ws;    ws += 256 * 4;
    int* bbase = (int*)ws;      ws += 257 * 4;
    int* csr_src = (int*)ws;    ws += (size_t)E * 4;
    u16* Wt1 = (u16*)ws;        ws += 65536 * 2;
    u16* Wt2 = (u16*)ws;        ws += 65536 * 2;
    ws = (char*)(((uintptr_t)ws + 127) & ~(uintptr_t)127);
    int2* rec = (int2*)ws;      ws += (size_t)NB * BSTRIDE * 8;
    ws = (char*)(((uintptr_t)ws + 127) & ~(uintptr_t)127);
    u16* g = (u16*)ws;          // n*256 bf16 (25.6 MB)
    u16* x1 = (u16*)d_out;      // bf16 x1 scratch in d_out; consumed by gemm2
                                // before final agg overwrites d_out

    prep_kernel<<<256, 256, 0, stream>>>(W1, W2, Wt1, Wt2, bcursor);
    scatter_kernel<<<(E + TILE - 1) / TILE, 256, 0, stream>>>(src, dst, bcursor, rec, E);
    bucket_scan<<<1, 256, 0, stream>>>(bcursor, bbase, row_ptr, NB, n, E);
    bucket_build<<<NB, 256, 0, stream>>>(rec, bcursor, bbase, row_ptr, dinv, csr_src, n);

    dim3 gg((n + 127) / 128, 2);
    // layer 1: g1 = bf16(dinv*(X@W1)); x1 = bf16(relu(dinv*(agg+self)+b1))
    mfma_gemm<true><<<gg, 256, 0, stream>>>(embedding, Wt1, dinv, g, n);
    agg_kernel<true><<<(n + 3) / 4, 256, 0, stream>>>(g, csr_src, row_ptr, dinv, b1, x1, n, 1);
    // layer 2: g2 = bf16(dinv*(x1@W2)); out = dinv*(agg+self)+b2 (f32)
    mfma_gemm<false><<<gg, 256, 0, stream>>>(x1, Wt2, dinv, g, n);
    agg_kernel<false><<<(n + 3) / 4, 256, 0, stream>>>(g, csr_src, row_ptr, dinv, b2, (float*)d_out, n, 0);
}